// Round 10
// baseline (263.388 us; speedup 1.0000x reference)
//
#include <hip/hip_runtime.h>
#include <math.h>

#define BB 4
#define CIN 256
#define GC 64
#define PL 64
#define HL 128
#define WL 128
#define HH 256
#define WW 256
#define HWLO (HL*WL)             /* 16384 */
#define HW (HH*WW)               /* 65536 */
#define NPIX (BB*HW)

typedef __attribute__((ext_vector_type(8))) short bf16x8;
typedef __attribute__((ext_vector_type(4))) float f32x4;

/* ws layout (bytes):
 *  xv   bf16 [0, 33554432)
 *  y1   fp32 [33554432, 50331648)   -- dead after k_conv_hi
 *  obuf bf16 [33554432, 67108864)   -- overlaps y1, written by k_attn
 *  stats     [67108864, 67109376)   -- 128 floats
 * peak 67.11 MB (<= 67.19 MB proven in R1). */
#define XV_OFF 0u
#define Y1_OFF 33554432u
#define OB_OFF 33554432u
#define STATS_OFF 67108864u

static __device__ __forceinline__ unsigned short f2bf(float f) {
    unsigned int u = __float_as_uint(f);
    u = (u + 0x7FFFu + ((u >> 16) & 1u)) >> 16;   /* RNE */
    return (unsigned short)u;
}
static __device__ __forceinline__ float bf2f(unsigned short s) {
    return __uint_as_float(((unsigned int)s) << 16);
}

/* y1[b][64][128*128] = W_x(64x256) * x — bf16 MFMA GEMM, register-prefetch
 * pipelined: chunk kt+1 loads issue while MFMA consumes chunk kt. */
__global__ __launch_bounds__(512) void k_gemm_lo(const float* __restrict__ x,
                                                 const float* __restrict__ Wc,
                                                 float* __restrict__ y1) {
    __shared__ unsigned short lw[64 * 264];   /* W bf16 [64][256+8] */
    __shared__ unsigned short la[128 * 40];   /* act bf16 [128 px][32+8 k] */
    int t = threadIdx.x;
    int b = blockIdx.x >> 7;
    int row = blockIdx.x & 127;
    int lane = t & 63, wid = t >> 6;
    int g = lane >> 4, fr = lane & 15;

    for (int i = t; i < 64 * 256; i += 512) {
        int m = i >> 8, k = i & 255;
        lw[m * 264 + k] = f2bf(Wc[m * 320 + k]);
    }

    f32x4 acc[4];
#pragma unroll
    for (int m = 0; m < 4; ++m) acc[m] = (f32x4){0.f, 0.f, 0.f, 0.f};

    const float* xb = x + (size_t)b * CIN * HWLO + row * WL;
    int px = t & 127, kg = t >> 7;

    short pk[8];
#pragma unroll
    for (int j = 0; j < 8; ++j)
        pk[j] = (short)f2bf(xb[(size_t)(kg * 8 + j) * HWLO + px]);

    for (int kt = 0; kt < 8; ++kt) {
        int k0 = kt * 32;
        __syncthreads();                       /* prev compute done with la */
        *(bf16x8*)(&la[px * 40 + kg * 8]) = *(bf16x8*)pk;
        __syncthreads();
        if (kt < 7) {                          /* prefetch kt+1 under MFMA */
#pragma unroll
            for (int j = 0; j < 8; ++j)
                pk[j] = (short)f2bf(xb[(size_t)(k0 + 32 + kg * 8 + j) * HWLO + px]);
        }
        bf16x8 bfr = *(const bf16x8*)(&la[(wid * 16 + fr) * 40 + g * 8]);
#pragma unroll
        for (int m = 0; m < 4; ++m) {
            bf16x8 af = *(const bf16x8*)(&lw[(m * 16 + fr) * 264 + k0 + g * 8]);
            acc[m] = __builtin_amdgcn_mfma_f32_16x16x32_bf16(af, bfr, acc[m], 0, 0, 0);
        }
    }

    float* yb = y1 + (size_t)b * 64 * HWLO + row * WL + wid * 16 + fr;
#pragma unroll
    for (int m = 0; m < 4; ++m)
#pragma unroll
        for (int r = 0; r < 4; ++r)
            yb[(size_t)(m * 16 + g * 4 + r) * HWLO] = acc[m][r];
}

/* xv[b][64][256*256] (bf16) = upsample(y1) + W_g(64x64) * guide. */
__global__ __launch_bounds__(512) void k_conv_hi(const float* __restrict__ guide,
                                                 const float* __restrict__ Wc,
                                                 const float* __restrict__ y1,
                                                 unsigned short* __restrict__ xv) {
    __shared__ unsigned short lg[256 * 72];
    __shared__ unsigned short lw[64 * 72];
    int t = threadIdx.x;
    int bid = blockIdx.x;
    int swz = (bid & 7) * 128 + (bid >> 3);
    int b = swz >> 8, h = swz & 255;
    int lane = t & 63, wid = t >> 6, g = lane >> 4, fr = lane & 15;

    for (int i = t; i < 64 * 64; i += 512) {
        int m = i >> 6, k = i & 63;
        lw[m * 72 + k] = f2bf(Wc[m * 320 + 256 + k]);
    }
    const float* gb = guide + (size_t)b * GC * HW + (size_t)h * WW;
#pragma unroll
    for (int q = 0; q < 4; ++q) {
        int a = t + q * 512;
        int px = a & 255, kg = a >> 8;
        short pk[8];
#pragma unroll
        for (int j = 0; j < 8; ++j)
            pk[j] = (short)f2bf(gb[(size_t)(kg * 8 + j) * HW + px]);
        *(bf16x8*)(&lg[px * 72 + kg * 8]) = *(bf16x8*)pk;
    }
    __syncthreads();

    f32x4 acc[4][2];
#pragma unroll
    for (int m = 0; m < 4; ++m)
#pragma unroll
        for (int n = 0; n < 2; ++n) acc[m][n] = (f32x4){0.f, 0.f, 0.f, 0.f};

#pragma unroll
    for (int kt = 0; kt < 2; ++kt) {
        bf16x8 bfr[2];
#pragma unroll
        for (int n = 0; n < 2; ++n)
            bfr[n] = *(const bf16x8*)(&lg[(wid * 32 + n * 16 + fr) * 72 + kt * 32 + g * 8]);
#pragma unroll
        for (int m = 0; m < 4; ++m) {
            bf16x8 af = *(const bf16x8*)(&lw[(m * 16 + fr) * 72 + kt * 32 + g * 8]);
#pragma unroll
            for (int n = 0; n < 2; ++n)
                acc[m][n] = __builtin_amdgcn_mfma_f32_16x16x32_bf16(af, bfr[n], acc[m][n], 0, 0, 0);
        }
    }
    __syncthreads();

    float* yb = (float*)lg;
    int m0 = h >> 1; int iy0, iy1; float wy0;
    if (h & 1) { iy0 = m0; iy1 = (m0 + 1 < HL) ? m0 + 1 : HL - 1; wy0 = 0.75f; }
    else       { iy0 = (m0 - 1 >= 0) ? m0 - 1 : 0; iy1 = m0;      wy0 = 0.25f; }
    float wy1 = 1.f - wy0;
    const float* y1b = y1 + (size_t)b * 64 * HWLO;
    for (int i = t; i < 64 * 128; i += 512) {
        int ch = i >> 7, ix = i & 127;
        yb[ch * 132 + ix] = wy0 * y1b[(size_t)ch * HWLO + iy0 * WL + ix]
                          + wy1 * y1b[(size_t)ch * HWLO + iy1 * WL + ix];
    }
    __syncthreads();

    int ix0v[2], ix1v[2]; float wx0v[2];
#pragma unroll
    for (int n = 0; n < 2; ++n) {
        int w = wid * 32 + n * 16 + fr;
        int mm = w >> 1;
        if (w & 1) { ix0v[n] = mm; ix1v[n] = (mm + 1 < WL) ? mm + 1 : WL - 1; wx0v[n] = 0.75f; }
        else       { ix0v[n] = (mm - 1 >= 0) ? mm - 1 : 0; ix1v[n] = mm;      wx0v[n] = 0.25f; }
    }
    unsigned short* xb = xv + (size_t)b * 64 * HW + (size_t)h * WW;
#pragma unroll
    for (int m = 0; m < 4; ++m)
#pragma unroll
        for (int n = 0; n < 2; ++n) {
            int w = wid * 32 + n * 16 + fr;
#pragma unroll
            for (int r = 0; r < 4; ++r) {
                int ch = m * 16 + g * 4 + r;
                float up = wx0v[n] * yb[ch * 132 + ix0v[n]]
                         + (1.f - wx0v[n]) * yb[ch * 132 + ix1v[n]];
                xb[(size_t)ch * HW + w] = f2bf(acc[m][n][r] + up);
            }
        }
}

/* local 3x3 attention, prefetch-pipelined; writes o as bf16 scratch and
 * atomicAdds per-block BN partials into stats (no pb array, no k_reduce). */
__global__ __launch_bounds__(256) void k_attn(const float* __restrict__ guide,
                                              const unsigned short* __restrict__ xv,
                                              unsigned short* __restrict__ obuf,
                                              float* __restrict__ stats) {
    __shared__ float ls[8][3][264];
    __shared__ float lo[8][256];
    __shared__ float part[64][2];
    int t = threadIdx.x;
    int bid = blockIdx.x;
    int swz = (bid & 7) * 128 + (bid >> 3);
    int b = swz >> 8, h = swz & 255;
    bool rok[3] = { h > 0, true, h < HH - 1 };
    int hr[3] = { h > 0 ? h - 1 : 0, h, h < HH - 1 ? h + 1 : HH - 1 };

    /* persistent halo zeros ([0] and [257] never overwritten by stage writes) */
    if (t < 48) { int cc = t / 6, rem = t % 6; ls[cc][rem >> 1][(rem & 1) ? 257 : 0] = 0.f; }
    if (t < 128) part[t >> 1][t & 1] = 0.f;

    float s[9];
#pragma unroll
    for (int k = 0; k < 9; ++k) s[k] = 0.f;

    /* ---- score phase: prefetch-pipelined ---- */
    const float* gB = guide + (size_t)b * GC * HW;
    float pf[24];
#pragma unroll
    for (int cc = 0; cc < 8; ++cc)
#pragma unroll
        for (int r = 0; r < 3; ++r)
            pf[cc * 3 + r] = rok[r] ? gB[(size_t)cc * HW + (size_t)hr[r] * WW + t] : 0.f;

    for (int c0 = 0; c0 < GC; c0 += 8) {
        __syncthreads();
#pragma unroll
        for (int cc = 0; cc < 8; ++cc)
#pragma unroll
            for (int r = 0; r < 3; ++r)
                ls[cc][r][1 + t] = pf[cc * 3 + r];
        __syncthreads();
        if (c0 + 8 < GC) {
#pragma unroll
            for (int cc = 0; cc < 8; ++cc)
#pragma unroll
                for (int r = 0; r < 3; ++r)
                    pf[cc * 3 + r] = rok[r] ? gB[(size_t)(c0 + 8 + cc) * HW + (size_t)hr[r] * WW + t] : 0.f;
        }
#pragma unroll
        for (int cc = 0; cc < 8; ++cc) {
            float q = ls[cc][1][1 + t];
#pragma unroll
            for (int r = 0; r < 3; ++r)
#pragma unroll
                for (int dj = 0; dj < 3; ++dj)
                    s[r * 3 + dj] = fmaf(q, ls[cc][r][t + dj], s[r * 3 + dj]);
        }
    }

    /* softmax over 9 (zero scores for OOB = reference zero-pad semantics) */
    float mx = s[0] * 0.125f;
#pragma unroll
    for (int k = 0; k < 9; ++k) { s[k] *= 0.125f; mx = fmaxf(mx, s[k]); }
    float den = 0.f;
#pragma unroll
    for (int k = 0; k < 9; ++k) { s[k] = __expf(s[k] - mx); den += s[k]; }
    float inv = 1.f / den;
#pragma unroll
    for (int k = 0; k < 9; ++k) s[k] *= inv;

    /* ---- PV phase: o -> bf16 scratch + fused block stats ---- */
    const unsigned short* vB = xv + (size_t)b * 64 * HW;
    unsigned short* oB = obuf + (size_t)b * 64 * HW + (size_t)h * WW + t;
    int rcc = t >> 5, rln = t & 31;

    unsigned short pfu[24];
#pragma unroll
    for (int cc = 0; cc < 8; ++cc)
#pragma unroll
        for (int r = 0; r < 3; ++r)
            pfu[cc * 3 + r] = rok[r] ? vB[(size_t)cc * HW + (size_t)hr[r] * WW + t] : (unsigned short)0;

    for (int c0 = 0; c0 < PL; c0 += 8) {
        __syncthreads();
#pragma unroll
        for (int cc = 0; cc < 8; ++cc)
#pragma unroll
            for (int r = 0; r < 3; ++r)
                ls[cc][r][1 + t] = bf2f(pfu[cc * 3 + r]);
        if (c0 > 0) {            /* reduce previous chunk's lo -> part */
            float sv = 0.f, qv = 0.f;
#pragma unroll
            for (int j = 0; j < 8; ++j) {
                float v = lo[rcc][rln + 32 * j];
                sv += v; qv = fmaf(v, v, qv);
            }
#pragma unroll
            for (int d = 16; d >= 1; d >>= 1) { sv += __shfl_xor(sv, d); qv += __shfl_xor(qv, d); }
            if (rln == 0) { part[c0 - 8 + rcc][0] += sv; part[c0 - 8 + rcc][1] += qv; }
        }
        __syncthreads();
        if (c0 + 8 < PL) {
#pragma unroll
            for (int cc = 0; cc < 8; ++cc)
#pragma unroll
                for (int r = 0; r < 3; ++r)
                    pfu[cc * 3 + r] = rok[r] ? vB[(size_t)(c0 + 8 + cc) * HW + (size_t)hr[r] * WW + t] : (unsigned short)0;
        }
#pragma unroll
        for (int cc = 0; cc < 8; ++cc) {
            float o = 0.f;
#pragma unroll
            for (int r = 0; r < 3; ++r)
#pragma unroll
                for (int dj = 0; dj < 3; ++dj)
                    o = fmaf(s[r * 3 + dj], ls[cc][r][t + dj], o);
            unsigned short ob = f2bf(o);
            float orv = bf2f(ob);            /* stats on the stored value */
            oB[(size_t)(c0 + cc) * HW] = ob;
            lo[cc][t] = orv;
        }
    }
    __syncthreads();
    {   /* reduce final chunk */
        float sv = 0.f, qv = 0.f;
#pragma unroll
        for (int j = 0; j < 8; ++j) {
            float v = lo[rcc][rln + 32 * j];
            sv += v; qv = fmaf(v, v, qv);
        }
#pragma unroll
        for (int d = 16; d >= 1; d >>= 1) { sv += __shfl_xor(sv, d); qv += __shfl_xor(qv, d); }
        if (rln == 0) { part[56 + rcc][0] += sv; part[56 + rcc][1] += qv; }
    }
    __syncthreads();
    if (t < 128) atomicAdd(&stats[(t & 1) * 64 + (t >> 1)], part[t >> 1][t & 1]);
}

/* normalize: read bf16 obuf (33.5MB), write fp32 out (67MB). */
__global__ __launch_bounds__(256) void k_norm(const unsigned short* __restrict__ obuf,
                                              const float* __restrict__ stats,
                                              const float* __restrict__ gamma,
                                              const float* __restrict__ beta,
                                              float* __restrict__ out) {
    size_t idx8 = (size_t)blockIdx.x * 256 + threadIdx.x;   /* 8-elem index */
    int c = (int)((idx8 >> 13) & 63);
    float n = (float)NPIX;
    float mean = stats[c] / n;
    float var = stats[64 + c] / n - mean * mean;
    float sc = gamma[c] * rsqrtf(var + 1e-5f);
    float bs = beta[c] - mean * sc;
    bf16x8 v = ((const bf16x8*)obuf)[idx8];
    float4 o0, o1;
    o0.x = fmaf(bf2f((unsigned short)v[0]), sc, bs);
    o0.y = fmaf(bf2f((unsigned short)v[1]), sc, bs);
    o0.z = fmaf(bf2f((unsigned short)v[2]), sc, bs);
    o0.w = fmaf(bf2f((unsigned short)v[3]), sc, bs);
    o1.x = fmaf(bf2f((unsigned short)v[4]), sc, bs);
    o1.y = fmaf(bf2f((unsigned short)v[5]), sc, bs);
    o1.z = fmaf(bf2f((unsigned short)v[6]), sc, bs);
    o1.w = fmaf(bf2f((unsigned short)v[7]), sc, bs);
    ((float4*)out)[idx8 * 2]     = o0;
    ((float4*)out)[idx8 * 2 + 1] = o1;
}

extern "C" void kernel_launch(void* const* d_in, const int* in_sizes, int n_in,
                              void* d_out, int out_size, void* d_ws, size_t ws_size,
                              hipStream_t stream) {
    const float* x     = (const float*)d_in[0];
    const float* guide = (const float*)d_in[1];
    const float* Wc    = (const float*)d_in[2];
    const float* gamma = (const float*)d_in[3];
    const float* beta  = (const float*)d_in[4];
    float* out = (float*)d_out;

    char* ws = (char*)d_ws;
    unsigned short* xvb  = (unsigned short*)(ws + XV_OFF);
    float* y1            = (float*)(ws + Y1_OFF);
    unsigned short* obuf = (unsigned short*)(ws + OB_OFF);
    float* stats         = (float*)(ws + STATS_OFF);

    hipMemsetAsync(stats, 0, 128 * sizeof(float), stream);
    k_gemm_lo<<<512, 512, 0, stream>>>(x, Wc, y1);
    k_conv_hi<<<1024, 512, 0, stream>>>(guide, Wc, y1, xvb);
    k_attn<<<1024, 256, 0, stream>>>(guide, xvb, obuf, stats);
    k_norm<<<(NPIX * PL) / (256 * 8), 256, 0, stream>>>(obuf, stats, gamma, beta, out);
}